// Round 14
// baseline (25.563 us; speedup 1.0000x reference)
//
#include <hip/hip_runtime.h>
#include <math.h>

#define BB 4
#define NN 2048
#define MM 128
#define DD 64
#define NEG_SLOPE 0.2f

#define MT 16                 // m per block
#define NMT (MM / MT)         // 8 m-tiles
#define NSPL 16               // n splits
#define NR (NN / NSPL)        // 128 n per block
#define PSTR 132              // p_lds row stride
#define QSTR 68               // q_tot row stride (bank-spread)

// ---------------------------------------------------------------------------
// K1: per (ns, mt, b) block — proj-free, 3 barriers, direct partial stores:
//  0 : stage fs chunk; v_l/u_r half-partials (256 thr, 32 iters); c_e
//  0b: el[n] = fs[n,:].v_l (inline 2-part) ; er[m] = fd[m,:].u_r (inline)
//  1 : scores p = exp(masked leaky)
//  2 : q[nq][m][k] partial = sum_n p*fs -> pacc directly ; denom/sfe -> pdn
// ---------------------------------------------------------------------------
__global__ __launch_bounds__(256, 3) void fused_kernel(
        const float* __restrict__ fs, const float* __restrict__ W_src,
        const float* __restrict__ attn_l,
        const float* __restrict__ fd, const float* __restrict__ W_dst,
        const float* __restrict__ attn_r,
        const float* __restrict__ W_edge, const float* __restrict__ attn_e,
        const float* __restrict__ fe, const int* __restrict__ adj,
        float* __restrict__ pacc, float* __restrict__ pdn) {
    int ns = blockIdx.x, mt = blockIdx.y, b = blockIdx.z;
    int n0 = ns * NR, m0 = mt * MT;
    int t = threadIdx.x;

    __shared__ __align__(16) float fsh[NR * DD];     // 32 KB
    __shared__ __align__(16) float p_lds[MT * PSTR]; // 8.25 KB
    __shared__ __align__(16) float vpart[2][DD];
    __shared__ __align__(16) float upart[2][DD];
    __shared__ float el_lds[NR];
    __shared__ float er_lds[MT];
    __shared__ float dred[16][17], fred[16][17];
    __shared__ float ce_s;

    // ---- phase 0: stage fs + split v_l/u_r partials + c_e ----
    const float4* fs4 = (const float4*)(fs + ((size_t)(b * NN + n0)) * DD);
#pragma unroll 4
    for (int k = 0; k < 8; ++k)
        ((float4*)fsh)[t + k * 256] = fs4[t + k * 256];

    {
        int k = t & 63, half = (t >> 6) & 1;
        if (t < 128) {                    // v_l partial halves
            float a = 0.f;
#pragma unroll
            for (int j = 0; j < 32; ++j) {
                int d2 = half * 32 + j;
                a += attn_l[d2] * W_src[d2 * DD + k];
            }
            vpart[half][k] = a;
        } else {                          // u_r partial halves
            float a = 0.f;
#pragma unroll
            for (int j = 0; j < 32; ++j) {
                int d2 = half * 32 + j;
                a += attn_r[d2] * W_dst[d2 * DD + k];
            }
            upart[half][k] = a;
        }
        if (t < 64) {                     // c_e (wave 0, after its partial)
            float v = W_edge[t] * attn_e[t];
#pragma unroll
            for (int off = 32; off > 0; off >>= 1) v += __shfl_xor(v, off, 64);
            if (t == 0) ce_s = v;
        }
    }
    __syncthreads();

    // ---- phase 0b: el (inline 2-part v_l) + er (inline 2-part u_r) ----
    if (t < NR) {
        int n = t;
        float a = 0.f;
#pragma unroll 8
        for (int j = 0; j < DD; ++j) {
            int kk = (n + j) & 63;        // rotation: <=2-way banks
            a += fsh[n * DD + kk] * (vpart[0][kk] + vpart[1][kk]);
        }
        el_lds[n] = a;
    } else if (t < NR + MT) {
        int m = t - NR;
        float a = 0.f;
        const float4* fd4 = (const float4*)(fd + (size_t)(b * MM + m0 + m) * DD);
#pragma unroll
        for (int k4 = 0; k4 < 16; ++k4) {
            float4 f = fd4[k4];
            float4 u0 = *(const float4*)&upart[0][k4 * 4];
            float4 u1 = *(const float4*)&upart[1][k4 * 4];
            a += f.x * (u0.x + u1.x) + f.y * (u0.y + u1.y) +
                 f.z * (u0.z + u1.z) + f.w * (u0.w + u1.w);
        }
        er_lds[m] = a;
    }
    __syncthreads();

    // ---- phase 1: scores (m = t&15, h = t>>4), n = h + 16j ----
    {
        int m = t & 15, h = t >> 4;
        float ce = ce_s;
        float er_m = er_lds[m];
        const float* fe_p = fe + ((size_t)(b * NN + n0)) * MM + m0 + m;
        const int* adj_p = adj + ((size_t)(b * NN + n0)) * MM + m0 + m;
        float dsum = 0.f, fsum = 0.f;
#pragma unroll 4
        for (int j = 0; j < 8; ++j) {
            int n = h + j * 16;
            float f = fe_p[(size_t)n * MM];
            int a = adj_p[(size_t)n * MM];
            float s = el_lds[n] + ce * f + er_m;
            s = s > 0.f ? s : NEG_SLOPE * s;
            float p = (a == 1) ? __expf(s) : 0.f;
            p_lds[m * PSTR + n] = p;
            dsum += p;
            fsum += f * p;
        }
        dred[h][m] = dsum;
        fred[h][m] = fsum;
    }
    __syncthreads();

    // ---- phase 2: q-agg + DIRECT stores (no more barriers) ----
    {
        int nq = t >> 6, mh = (t >> 5) & 1, kq = t & 31;
        float acc[8][2];
#pragma unroll
        for (int i = 0; i < 8; ++i) { acc[i][0] = 0.f; acc[i][1] = 0.f; }
        int rbase = mh * 8 * PSTR;
#pragma unroll 2
        for (int n4 = 0; n4 < 8; ++n4) {
            int nb = nq * 32 + n4 * 4;
            float2 h0 = *(const float2*)&fsh[(nb + 0) * DD + kq * 2];
            float2 h1 = *(const float2*)&fsh[(nb + 1) * DD + kq * 2];
            float2 h2 = *(const float2*)&fsh[(nb + 2) * DD + kq * 2];
            float2 h3 = *(const float2*)&fsh[(nb + 3) * DD + kq * 2];
#pragma unroll
            for (int mj = 0; mj < 8; ++mj) {
                float4 p4 = *(const float4*)&p_lds[rbase + mj * PSTR + nb];
                acc[mj][0] += p4.x * h0.x + p4.y * h1.x + p4.z * h2.x + p4.w * h3.x;
                acc[mj][1] += p4.x * h0.y + p4.y * h1.y + p4.z * h2.y + p4.w * h3.y;
            }
        }
        // pacc slot = ((b,mt,ns)*4 + nq); rows m, cols k — coalesced float2
        size_t pbase = ((size_t)((b * NMT + mt) * NSPL + ns) * 4 + nq) * MT;
#pragma unroll
        for (int mj = 0; mj < 8; ++mj) {
            int m = mh * 8 + mj;
            *(float2*)&pacc[(pbase + m) * DD + kq * 2] =
                make_float2(acc[mj][0], acc[mj][1]);
        }
    }
    if (t < MT) {
        float ds2 = 0.f, fs2 = 0.f;
#pragma unroll
        for (int k = 0; k < 16; ++k) { ds2 += dred[k][t]; fs2 += fred[k][t]; }
        size_t q = ((size_t)((b * NMT + mt) * NSPL + ns) * MT + t) * 2;
        pdn[q] = ds2;
        pdn[q + 1] = fs2;
    }
}

// ---------------------------------------------------------------------------
// K2: per (mt, b): q_tot = sum over 64 partial slots; out = sigmoid(
//     (W_src.q_tot + W_edge*sfe)/denom) — 32 blocks.
// ---------------------------------------------------------------------------
__global__ __launch_bounds__(256) void finish_kernel(
        const float* __restrict__ pacc, const float* __restrict__ pdn,
        const float* __restrict__ W_src, const float* __restrict__ W_edge,
        float* __restrict__ out) {
    int mt = blockIdx.x, b = blockIdx.y;
    int m0 = mt * MT;
    int t = threadIdx.x;

    __shared__ __align__(16) float WT[DD * DD];       // [k][d] = W_src[d][k]
    __shared__ __align__(16) float q_tot[MT * QSTR];
    __shared__ float dn_tot[MT], sf_tot[MT];

#pragma unroll
    for (int i = 0; i < 16; ++i) {
        int idx = t + i * 256;            // 0..4095
        int k = idx >> 6, d = idx & 63;
        WT[idx] = W_src[d * DD + k];
    }
    {
        int m = t >> 4, kq = t & 15;
        size_t base = (size_t)((b * NMT + mt) * NSPL) * 4;
        float4 s = make_float4(0.f, 0.f, 0.f, 0.f);
#pragma unroll 8
        for (int sj = 0; sj < NSPL * 4; ++sj) {
            float4 v = *(const float4*)&pacc[((base + sj) * MT + m) * DD + kq * 4];
            s.x += v.x; s.y += v.y; s.z += v.z; s.w += v.w;
        }
        *(float4*)&q_tot[m * QSTR + kq * 4] = s;
    }
    if (t < MT) {
        size_t base = (size_t)((b * NMT + mt) * NSPL) * MT;
        float ds2 = 0.f, fs2 = 0.f;
#pragma unroll
        for (int nsj = 0; nsj < NSPL; ++nsj) {
            size_t q = (base + nsj * MT + t) * 2;
            ds2 += pdn[q];
            fs2 += pdn[q + 1];
        }
        dn_tot[t] = ds2;
        sf_tot[t] = fs2;
    }
    __syncthreads();
    {
        int m = t >> 4, dq = t & 15;
        float4 r = make_float4(0.f, 0.f, 0.f, 0.f);
#pragma unroll 8
        for (int k = 0; k < DD; ++k) {
            float qv = q_tot[m * QSTR + k];
            float4 wv = *(const float4*)&WT[k * DD + dq * 4];
            r.x += wv.x * qv; r.y += wv.y * qv;
            r.z += wv.z * qv; r.w += wv.w * qv;
        }
        float inv = 1.f / dn_tot[m];
        float sfe = sf_tot[m];
        float4 we = *(const float4*)&W_edge[dq * 4];
        float4 o;
        o.x = 1.f / (1.f + __expf(-(we.x * sfe + r.x) * inv));
        o.y = 1.f / (1.f + __expf(-(we.y * sfe + r.y) * inv));
        o.z = 1.f / (1.f + __expf(-(we.z * sfe + r.z) * inv));
        o.w = 1.f / (1.f + __expf(-(we.w * sfe + r.w) * inv));
        *(float4*)&out[((size_t)(b * MM + m0 + m)) * DD + dq * 4] = o;
    }
}

extern "C" void kernel_launch(void* const* d_in, const int* in_sizes, int n_in,
                              void* d_out, int out_size, void* d_ws, size_t ws_size,
                              hipStream_t stream) {
    const float* feat_src  = (const float*)d_in[0];
    const float* feat_dst  = (const float*)d_in[1];
    const float* feat_edge = (const float*)d_in[2];
    const int*   adj       = (const int*)d_in[3];
    const float* W_src     = (const float*)d_in[4];
    const float* W_dst     = (const float*)d_in[5];
    const float* W_edge    = (const float*)d_in[6];
    const float* attn_l    = (const float*)d_in[7];
    const float* attn_r    = (const float*)d_in[8];
    const float* attn_e    = (const float*)d_in[9];
    float* out = (float*)d_out;

    float* ws   = (float*)d_ws;
    float* pacc = ws;                                            // 2097152
    float* pdn  = pacc + (size_t)BB * NMT * NSPL * 4 * MT * DD;  // 16384

    fused_kernel<<<dim3(NSPL, NMT, BB), 256, 0, stream>>>(
        feat_src, W_src, attn_l, feat_dst, W_dst, attn_r,
        W_edge, attn_e, feat_edge, adj, pacc, pdn);
    finish_kernel<<<dim3(NMT, BB), 256, 0, stream>>>(
        pacc, pdn, W_src, W_edge, out);
}

// Round 15
// 20.386 us; speedup vs baseline: 1.2540x; 1.2540x over previous
//
#include <hip/hip_runtime.h>
#include <math.h>

#define BB 4
#define NN 2048
#define MM 128
#define DD 64
#define NEG_SLOPE 0.2f

#define MT 16                 // m per block
#define NMT (MM / MT)         // 8 m-tiles
#define NSPL 16               // n splits
#define NR (NN / NSPL)        // 128 n per block
#define PSTR 132              // p_lds row stride
#define QSTR 68               // q_tot row stride (bank-spread)

// ---------------------------------------------------------------------------
// K1: per (ns, mt, b) block — proj-free (fs-space aggregation):
//  entry: prefetch fe/adj for phase 1 (T14: HBM latency hides under phase 0)
//  0 : stage fs chunk; v_l/u_r half-partials (32-deep, 4 waves); c_e
//  0b: el[n] = fs[n,:].v_l ; er[m] = fd[m,:].u_r  (inline 2-part sums)
//  1 : scores p = exp(masked leaky)  (consumes prefetch)
//  2 : q[m,k] partial = sum_n p*fs -> in-block reduce -> pacc ; pdn
// ---------------------------------------------------------------------------
__global__ __launch_bounds__(256, 3) void fused_kernel(
        const float* __restrict__ fs, const float* __restrict__ W_src,
        const float* __restrict__ attn_l,
        const float* __restrict__ fd, const float* __restrict__ W_dst,
        const float* __restrict__ attn_r,
        const float* __restrict__ W_edge, const float* __restrict__ attn_e,
        const float* __restrict__ fe, const int* __restrict__ adj,
        float* __restrict__ pacc, float* __restrict__ pdn) {
    int ns = blockIdx.x, mt = blockIdx.y, b = blockIdx.z;
    int n0 = ns * NR, m0 = mt * MT;
    int t = threadIdx.x;

    __shared__ __align__(16) float fsh[NR * DD];     // 32 KB: fs, then partials
    __shared__ __align__(16) float p_lds[MT * PSTR]; // 8.25 KB
    __shared__ __align__(16) float vpart[2][DD];
    __shared__ __align__(16) float upart[2][DD];
    __shared__ float el_lds[NR];
    __shared__ float er_lds[MT];
    __shared__ float dred[16][17], fred[16][17];
    __shared__ float ce_s;

    // ---- entry: prefetch fe/adj for phase 1 ----
    int pm = t & 15, ph = t >> 4;
    const float* fe_p = fe + ((size_t)(b * NN + n0)) * MM + m0 + pm;
    const int* adj_p = adj + ((size_t)(b * NN + n0)) * MM + m0 + pm;
    float fe_loc[8];
    int adj_loc[8];
#pragma unroll
    for (int j = 0; j < 8; ++j) {
        int n = ph + j * 16;
        fe_loc[j] = fe_p[(size_t)n * MM];
        adj_loc[j] = adj_p[(size_t)n * MM];
    }

    // ---- phase 0: stage fs + split v_l/u_r partials + c_e ----
    const float4* fs4 = (const float4*)(fs + ((size_t)(b * NN + n0)) * DD);
#pragma unroll 4
    for (int k = 0; k < 8; ++k)
        ((float4*)fsh)[t + k * 256] = fs4[t + k * 256];

    {
        int k = t & 63, half = (t >> 6) & 1;
        if (t < 128) {                    // v_l partial halves (32-deep)
            float a = 0.f;
#pragma unroll
            for (int j = 0; j < 32; ++j) {
                int d2 = half * 32 + j;
                a += attn_l[d2] * W_src[d2 * DD + k];
            }
            vpart[half][k] = a;
        } else {                          // u_r partial halves
            float a = 0.f;
#pragma unroll
            for (int j = 0; j < 32; ++j) {
                int d2 = half * 32 + j;
                a += attn_r[d2] * W_dst[d2 * DD + k];
            }
            upart[half][k] = a;
        }
        if (t < 64) {                     // c_e (wave 0, after its partial)
            float v = W_edge[t] * attn_e[t];
#pragma unroll
            for (int off = 32; off > 0; off >>= 1) v += __shfl_xor(v, off, 64);
            if (t == 0) ce_s = v;
        }
    }
    __syncthreads();

    // ---- phase 0b: el (inline 2-part v_l) + er (inline 2-part u_r) ----
    if (t < NR) {
        int n = t;
        float a = 0.f;
#pragma unroll 8
        for (int j = 0; j < DD; ++j) {
            int kk = (n + j) & 63;        // rotation: <=2-way banks
            a += fsh[n * DD + kk] * (vpart[0][kk] + vpart[1][kk]);
        }
        el_lds[n] = a;
    } else if (t < NR + MT) {
        int m = t - NR;
        float a = 0.f;
        const float4* fd4 = (const float4*)(fd + (size_t)(b * MM + m0 + m) * DD);
#pragma unroll
        for (int k4 = 0; k4 < 16; ++k4) {
            float4 f = fd4[k4];
            float4 u0 = *(const float4*)&upart[0][k4 * 4];
            float4 u1 = *(const float4*)&upart[1][k4 * 4];
            a += f.x * (u0.x + u1.x) + f.y * (u0.y + u1.y) +
                 f.z * (u0.z + u1.z) + f.w * (u0.w + u1.w);
        }
        er_lds[m] = a;
    }
    __syncthreads();

    // ---- phase 1: scores (m = pm, h = ph), n = h + 16j — uses prefetch ----
    {
        float ce = ce_s;
        float er_m = er_lds[pm];
        float dsum = 0.f, fsum = 0.f;
#pragma unroll
        for (int j = 0; j < 8; ++j) {
            int n = ph + j * 16;
            float f = fe_loc[j];
            float s = el_lds[n] + ce * f + er_m;
            s = s > 0.f ? s : NEG_SLOPE * s;
            float p = (adj_loc[j] == 1) ? __expf(s) : 0.f;
            p_lds[pm * PSTR + n] = p;
            dsum += p;
            fsum += f * p;
        }
        dred[ph][pm] = dsum;
        fred[ph][pm] = fsum;
    }
    __syncthreads();

    // ---- phase 2: q-agg (nq = t>>6, mh = (t>>5)&1, kq = t&31) ----
    float acc[8][2];
    {
        int nq = t >> 6, mh = (t >> 5) & 1, kq = t & 31;
#pragma unroll
        for (int i = 0; i < 8; ++i) { acc[i][0] = 0.f; acc[i][1] = 0.f; }
        int rbase = mh * 8 * PSTR;
#pragma unroll 2
        for (int n4 = 0; n4 < 8; ++n4) {
            int nb = nq * 32 + n4 * 4;
            float2 h0 = *(const float2*)&fsh[(nb + 0) * DD + kq * 2];
            float2 h1 = *(const float2*)&fsh[(nb + 1) * DD + kq * 2];
            float2 h2 = *(const float2*)&fsh[(nb + 2) * DD + kq * 2];
            float2 h3 = *(const float2*)&fsh[(nb + 3) * DD + kq * 2];
#pragma unroll
            for (int mj = 0; mj < 8; ++mj) {
                float4 p4 = *(const float4*)&p_lds[rbase + mj * PSTR + nb];
                acc[mj][0] += p4.x * h0.x + p4.y * h1.x + p4.z * h2.x + p4.w * h3.x;
                acc[mj][1] += p4.x * h0.y + p4.y * h1.y + p4.z * h2.y + p4.w * h3.y;
            }
        }
    }
    __syncthreads();                      // agg reads of fsh done

    // ---- partials into fsh[nq][m][k] ----
    {
        int nq = t >> 6, mh = (t >> 5) & 1, kq = t & 31;
        float* part = fsh + nq * (MT * DD);
#pragma unroll
        for (int mj = 0; mj < 8; ++mj)
            *(float2*)&part[(mh * 8 + mj) * DD + kq * 2] =
                make_float2(acc[mj][0], acc[mj][1]);
    }
    __syncthreads();

    // ---- sum 4 partials -> pacc (q); pdn ----
    size_t pbase = (size_t)((b * NMT + mt) * NSPL + ns) * MT;
    {
        int m = t >> 4, ks = t & 15;
        float4 s0 = *(const float4*)&fsh[0 * MT * DD + m * DD + ks * 4];
        float4 s1 = *(const float4*)&fsh[1 * MT * DD + m * DD + ks * 4];
        float4 s2 = *(const float4*)&fsh[2 * MT * DD + m * DD + ks * 4];
        float4 s3 = *(const float4*)&fsh[3 * MT * DD + m * DD + ks * 4];
        float4 o;
        o.x = s0.x + s1.x + s2.x + s3.x;
        o.y = s0.y + s1.y + s2.y + s3.y;
        o.z = s0.z + s1.z + s2.z + s3.z;
        o.w = s0.w + s1.w + s2.w + s3.w;
        *(float4*)&pacc[(pbase + m) * DD + ks * 4] = o;
    }
    if (t < MT) {
        float ds2 = 0.f, fs2 = 0.f;
#pragma unroll
        for (int k = 0; k < 16; ++k) { ds2 += dred[k][t]; fs2 += fred[k][t]; }
        size_t q = (pbase + t) * 2;
        pdn[q] = ds2;
        pdn[q + 1] = fs2;
    }
}

// ---------------------------------------------------------------------------
// K2: per (mt, b) block: q_tot = sum_ns pacc; out = sigmoid((W_src.q_tot +
//     W_edge*sfe)/denom)  — 32 blocks, tiny.
// ---------------------------------------------------------------------------
__global__ __launch_bounds__(256) void finish_kernel(
        const float* __restrict__ pacc, const float* __restrict__ pdn,
        const float* __restrict__ W_src, const float* __restrict__ W_edge,
        float* __restrict__ out) {
    int mt = blockIdx.x, b = blockIdx.y;
    int m0 = mt * MT;
    int t = threadIdx.x;

    __shared__ __align__(16) float WT[DD * DD];       // [k][d] = W_src[d][k]
    __shared__ __align__(16) float q_tot[MT * QSTR];
    __shared__ float dn_tot[MT], sf_tot[MT];

#pragma unroll
    for (int i = 0; i < 16; ++i) {
        int idx = t + i * 256;            // 0..4095
        int k = idx >> 6, d = idx & 63;
        WT[idx] = W_src[d * DD + k];
    }
    {
        int m = t >> 4, kq = t & 15;
        size_t base = (size_t)((b * NMT + mt) * NSPL) * MT;
        float4 s = make_float4(0.f, 0.f, 0.f, 0.f);
#pragma unroll
        for (int nsj = 0; nsj < NSPL; ++nsj) {
            float4 v = *(const float4*)&pacc[(base + nsj * MT + m) * DD + kq * 4];
            s.x += v.x; s.y += v.y; s.z += v.z; s.w += v.w;
        }
        *(float4*)&q_tot[m * QSTR + kq * 4] = s;
    }
    if (t < MT) {
        size_t base = (size_t)((b * NMT + mt) * NSPL) * MT;
        float ds2 = 0.f, fs2 = 0.f;
#pragma unroll
        for (int nsj = 0; nsj < NSPL; ++nsj) {
            size_t q = (base + nsj * MT + t) * 2;
            ds2 += pdn[q];
            fs2 += pdn[q + 1];
        }
        dn_tot[t] = ds2;
        sf_tot[t] = fs2;
    }
    __syncthreads();
    {
        int m = t >> 4, dq = t & 15;
        float4 r = make_float4(0.f, 0.f, 0.f, 0.f);
#pragma unroll 8
        for (int k = 0; k < DD; ++k) {
            float qv = q_tot[m * QSTR + k];
            float4 wv = *(const float4*)&WT[k * DD + dq * 4];
            r.x += wv.x * qv; r.y += wv.y * qv;
            r.z += wv.z * qv; r.w += wv.w * qv;
        }
        float inv = 1.f / dn_tot[m];
        float sfe = sf_tot[m];
        float4 we = *(const float4*)&W_edge[dq * 4];
        float4 o;
        o.x = 1.f / (1.f + __expf(-(we.x * sfe + r.x) * inv));
        o.y = 1.f / (1.f + __expf(-(we.y * sfe + r.y) * inv));
        o.z = 1.f / (1.f + __expf(-(we.z * sfe + r.z) * inv));
        o.w = 1.f / (1.f + __expf(-(we.w * sfe + r.w) * inv));
        *(float4*)&out[((size_t)(b * MM + m0 + m)) * DD + dq * 4] = o;
    }
}

extern "C" void kernel_launch(void* const* d_in, const int* in_sizes, int n_in,
                              void* d_out, int out_size, void* d_ws, size_t ws_size,
                              hipStream_t stream) {
    const float* feat_src  = (const float*)d_in[0];
    const float* feat_dst  = (const float*)d_in[1];
    const float* feat_edge = (const float*)d_in[2];
    const int*   adj       = (const int*)d_in[3];
    const float* W_src     = (const float*)d_in[4];
    const float* W_dst     = (const float*)d_in[5];
    const float* W_edge    = (const float*)d_in[6];
    const float* attn_l    = (const float*)d_in[7];
    const float* attn_r    = (const float*)d_in[8];
    const float* attn_e    = (const float*)d_in[9];
    float* out = (float*)d_out;

    float* ws   = (float*)d_ws;
    float* pacc = ws;                                        // 524288
    float* pdn  = pacc + (size_t)BB * NMT * NSPL * MT * DD;  // 16384

    fused_kernel<<<dim3(NSPL, NMT, BB), 256, 0, stream>>>(
        feat_src, W_src, attn_l, feat_dst, W_dst, attn_r,
        W_edge, attn_e, feat_edge, adj, pacc, pdn);
    finish_kernel<<<dim3(NMT, BB), 256, 0, stream>>>(
        pacc, pdn, W_src, W_edge, out);
}

// Round 16
// 19.876 us; speedup vs baseline: 1.2861x; 1.0256x over previous
//
#include <hip/hip_runtime.h>
#include <math.h>

#define BB 4
#define NN 2048
#define MM 128
#define DD 64
#define NEG_SLOPE 0.2f

#define MT 16                 // m per block
#define NMT (MM / MT)         // 8 m-tiles
#define NSPL 16               // n splits
#define NR (NN / NSPL)        // 128 n per block
#define PSTR 132              // p_lds row stride
#define QSTR 68               // q_tot row stride (bank-spread)

// ---------------------------------------------------------------------------
// K1: per (ns, mt, b) block — proj-free (fs-space aggregation):
//  0 : stage fs chunk; v_l = W_src^T.attn_l ; u_r = W_dst^T.attn_r ; c_e
//  0b: el[n] = fs[n,:].v_l ; er[m] = fd[m,:].u_r
//  1 : scores p = exp(masked leaky)
//  2 : q[m,k] partial = sum_n p*fs  -> pacc ; denom/sfe -> pdn
// ---------------------------------------------------------------------------
__global__ __launch_bounds__(256, 3) void fused_kernel(
        const float* __restrict__ fs, const float* __restrict__ W_src,
        const float* __restrict__ attn_l,
        const float* __restrict__ fd, const float* __restrict__ W_dst,
        const float* __restrict__ attn_r,
        const float* __restrict__ W_edge, const float* __restrict__ attn_e,
        const float* __restrict__ fe, const int* __restrict__ adj,
        float* __restrict__ pacc, float* __restrict__ pdn) {
    int ns = blockIdx.x, mt = blockIdx.y, b = blockIdx.z;
    int n0 = ns * NR, m0 = mt * MT;
    int t = threadIdx.x, lane = t & 63;

    __shared__ __align__(16) float fsh[NR * DD];     // 32 KB: fs, then partials
    __shared__ __align__(16) float p_lds[MT * PSTR]; // 8.25 KB
    __shared__ float el_lds[NR];
    __shared__ float er_lds[MT];
    __shared__ float vl[DD], ur[DD];
    __shared__ float dred[16][17], fred[16][17];
    __shared__ float ce_s;

    // ---- phase 0 ----
    const float4* fs4 = (const float4*)(fs + ((size_t)(b * NN + n0)) * DD);
#pragma unroll 4
    for (int k = 0; k < 8; ++k)
        ((float4*)fsh)[t + k * 256] = fs4[t + k * 256];

    if (t < 64) {                         // v_l = W_src^T . attn_l
        float a = 0.f;
#pragma unroll 8
        for (int d2 = 0; d2 < DD; ++d2) a += attn_l[d2] * W_src[d2 * DD + t];
        vl[t] = a;
    } else if (t < 128) {                 // u_r = W_dst^T . attn_r
        float a = 0.f;
#pragma unroll 8
        for (int d2 = 0; d2 < DD; ++d2) a += attn_r[d2] * W_dst[d2 * DD + lane];
        ur[lane] = a;
    } else if (t < 192) {                 // c_e
        float v = W_edge[lane] * attn_e[lane];
#pragma unroll
        for (int off = 32; off > 0; off >>= 1) v += __shfl_xor(v, off, 64);
        if (lane == 0) ce_s = v;
    }
    __syncthreads();

    // ---- phase 0b: el + er ----
    if (t < NR) {
        int n = t;
        float a = 0.f;
#pragma unroll 8
        for (int j = 0; j < DD; ++j) {
            int k = (n + j) & 63;         // rotation: <=2-way banks
            a += fsh[n * DD + k] * vl[k];
        }
        el_lds[n] = a;
    } else if (t < 128 + MT) {
        int m = t - 128;
        float a = 0.f;
        const float* fdp = fd + (size_t)(b * MM + m0 + m) * DD;
#pragma unroll 8
        for (int k = 0; k < DD; ++k) a += fdp[k] * ur[k];
        er_lds[m] = a;
    }
    __syncthreads();

    // ---- phase 1: scores (m = t&15, h = t>>4), n = h + 16j ----
    {
        int m = t & 15, h = t >> 4;
        float ce = ce_s;
        float er_m = er_lds[m];
        const float* fe_p = fe + ((size_t)(b * NN + n0)) * MM + m0 + m;
        const int* adj_p = adj + ((size_t)(b * NN + n0)) * MM + m0 + m;
        float dsum = 0.f, fsum = 0.f;
#pragma unroll 4
        for (int j = 0; j < 8; ++j) {
            int n = h + j * 16;
            float f = fe_p[(size_t)n * MM];
            int a = adj_p[(size_t)n * MM];
            float s = el_lds[n] + ce * f + er_m;
            s = s > 0.f ? s : NEG_SLOPE * s;
            float p = (a == 1) ? __expf(s) : 0.f;
            p_lds[m * PSTR + n] = p;
            dsum += p;
            fsum += f * p;
        }
        dred[h][m] = dsum;
        fred[h][m] = fsum;
    }
    __syncthreads();

    // ---- phase 2: q-agg (nq = t>>6, mh = (t>>5)&1, kq = t&31) ----
    float acc[8][2];
    {
        int nq = t >> 6, mh = (t >> 5) & 1, kq = t & 31;
#pragma unroll
        for (int i = 0; i < 8; ++i) { acc[i][0] = 0.f; acc[i][1] = 0.f; }
        int rbase = mh * 8 * PSTR;
#pragma unroll 2
        for (int n4 = 0; n4 < 8; ++n4) {
            int nb = nq * 32 + n4 * 4;
            float2 h0 = *(const float2*)&fsh[(nb + 0) * DD + kq * 2];
            float2 h1 = *(const float2*)&fsh[(nb + 1) * DD + kq * 2];
            float2 h2 = *(const float2*)&fsh[(nb + 2) * DD + kq * 2];
            float2 h3 = *(const float2*)&fsh[(nb + 3) * DD + kq * 2];
#pragma unroll
            for (int mj = 0; mj < 8; ++mj) {
                float4 p4 = *(const float4*)&p_lds[rbase + mj * PSTR + nb];
                acc[mj][0] += p4.x * h0.x + p4.y * h1.x + p4.z * h2.x + p4.w * h3.x;
                acc[mj][1] += p4.x * h0.y + p4.y * h1.y + p4.z * h2.y + p4.w * h3.y;
            }
        }
    }
    __syncthreads();                      // agg reads of fsh done

    // ---- partials into fsh[nq][m][k] ----
    {
        int nq = t >> 6, mh = (t >> 5) & 1, kq = t & 31;
        float* part = fsh + nq * (MT * DD);
#pragma unroll
        for (int mj = 0; mj < 8; ++mj)
            *(float2*)&part[(mh * 8 + mj) * DD + kq * 2] =
                make_float2(acc[mj][0], acc[mj][1]);
    }
    __syncthreads();

    // ---- sum 4 partials -> pacc (q); pdn ----
    size_t pbase = (size_t)((b * NMT + mt) * NSPL + ns) * MT;
    {
        int m = t >> 4, ks = t & 15;
        float4 s0 = *(const float4*)&fsh[0 * MT * DD + m * DD + ks * 4];
        float4 s1 = *(const float4*)&fsh[1 * MT * DD + m * DD + ks * 4];
        float4 s2 = *(const float4*)&fsh[2 * MT * DD + m * DD + ks * 4];
        float4 s3 = *(const float4*)&fsh[3 * MT * DD + m * DD + ks * 4];
        float4 o;
        o.x = s0.x + s1.x + s2.x + s3.x;
        o.y = s0.y + s1.y + s2.y + s3.y;
        o.z = s0.z + s1.z + s2.z + s3.z;
        o.w = s0.w + s1.w + s2.w + s3.w;
        *(float4*)&pacc[(pbase + m) * DD + ks * 4] = o;
    }
    if (t < MT) {
        float ds2 = 0.f, fs2 = 0.f;
#pragma unroll
        for (int k = 0; k < 16; ++k) { ds2 += dred[k][t]; fs2 += fred[k][t]; }
        size_t q = (pbase + t) * 2;
        pdn[q] = ds2;
        pdn[q + 1] = fs2;
    }
}

// ---------------------------------------------------------------------------
// K2: per (mt, b) block: q_tot = sum_ns pacc; out = sigmoid((W_src.q_tot +
//     W_edge*sfe)/denom)  — 32 blocks, tiny.
// ---------------------------------------------------------------------------
__global__ __launch_bounds__(256) void finish_kernel(
        const float* __restrict__ pacc, const float* __restrict__ pdn,
        const float* __restrict__ W_src, const float* __restrict__ W_edge,
        float* __restrict__ out) {
    int mt = blockIdx.x, b = blockIdx.y;
    int m0 = mt * MT;
    int t = threadIdx.x;

    __shared__ __align__(16) float WT[DD * DD];       // [k][d] = W_src[d][k]
    __shared__ __align__(16) float q_tot[MT * QSTR];
    __shared__ float dn_tot[MT], sf_tot[MT];

#pragma unroll
    for (int i = 0; i < 16; ++i) {
        int idx = t + i * 256;            // 0..4095
        int k = idx >> 6, d = idx & 63;
        WT[idx] = W_src[d * DD + k];
    }
    {
        int m = t >> 4, kq = t & 15;
        size_t base = (size_t)((b * NMT + mt) * NSPL) * MT;
        float4 s = make_float4(0.f, 0.f, 0.f, 0.f);
#pragma unroll
        for (int nsj = 0; nsj < NSPL; ++nsj) {
            float4 v = *(const float4*)&pacc[(base + nsj * MT + m) * DD + kq * 4];
            s.x += v.x; s.y += v.y; s.z += v.z; s.w += v.w;
        }
        *(float4*)&q_tot[m * QSTR + kq * 4] = s;
    }
    if (t < MT) {
        size_t base = (size_t)((b * NMT + mt) * NSPL) * MT;
        float ds2 = 0.f, fs2 = 0.f;
#pragma unroll
        for (int nsj = 0; nsj < NSPL; ++nsj) {
            size_t q = (base + nsj * MT + t) * 2;
            ds2 += pdn[q];
            fs2 += pdn[q + 1];
        }
        dn_tot[t] = ds2;
        sf_tot[t] = fs2;
    }
    __syncthreads();
    {
        int m = t >> 4, dq = t & 15;
        float4 r = make_float4(0.f, 0.f, 0.f, 0.f);
#pragma unroll 8
        for (int k = 0; k < DD; ++k) {
            float qv = q_tot[m * QSTR + k];
            float4 wv = *(const float4*)&WT[k * DD + dq * 4];
            r.x += wv.x * qv; r.y += wv.y * qv;
            r.z += wv.z * qv; r.w += wv.w * qv;
        }
        float inv = 1.f / dn_tot[m];
        float sfe = sf_tot[m];
        float4 we = *(const float4*)&W_edge[dq * 4];
        float4 o;
        o.x = 1.f / (1.f + __expf(-(we.x * sfe + r.x) * inv));
        o.y = 1.f / (1.f + __expf(-(we.y * sfe + r.y) * inv));
        o.z = 1.f / (1.f + __expf(-(we.z * sfe + r.z) * inv));
        o.w = 1.f / (1.f + __expf(-(we.w * sfe + r.w) * inv));
        *(float4*)&out[((size_t)(b * MM + m0 + m)) * DD + dq * 4] = o;
    }
}

extern "C" void kernel_launch(void* const* d_in, const int* in_sizes, int n_in,
                              void* d_out, int out_size, void* d_ws, size_t ws_size,
                              hipStream_t stream) {
    const float* feat_src  = (const float*)d_in[0];
    const float* feat_dst  = (const float*)d_in[1];
    const float* feat_edge = (const float*)d_in[2];
    const int*   adj       = (const int*)d_in[3];
    const float* W_src     = (const float*)d_in[4];
    const float* W_dst     = (const float*)d_in[5];
    const float* W_edge    = (const float*)d_in[6];
    const float* attn_l    = (const float*)d_in[7];
    const float* attn_r    = (const float*)d_in[8];
    const float* attn_e    = (const float*)d_in[9];
    float* out = (float*)d_out;

    float* ws   = (float*)d_ws;
    float* pacc = ws;                                        // 524288
    float* pdn  = pacc + (size_t)BB * NMT * NSPL * MT * DD;  // 16384

    fused_kernel<<<dim3(NSPL, NMT, BB), 256, 0, stream>>>(
        feat_src, W_src, attn_l, feat_dst, W_dst, attn_r,
        W_edge, attn_e, feat_edge, adj, pacc, pdn);
    finish_kernel<<<dim3(NMT, BB), 256, 0, stream>>>(
        pacc, pdn, W_src, W_edge, out);
}